// Round 1
// 12205.659 us; speedup vs baseline: 1.1176x; 1.1176x over previous
//
#include <hip/hip_runtime.h>

#define TT 2048
#define BB 32
#define HH 512
#define NWG 32

typedef _Float16 half8 __attribute__((ext_vector_type(8)));
typedef float f32x4 __attribute__((ext_vector_type(4)));

__device__ __forceinline__ float fsig(float x) { return 1.f / (1.f + __expf(-x)); }
__device__ __forceinline__ float ftanh_(float x) {
  x = fminf(fmaxf(x, -15.f), 15.f);
  float e = __expf(2.f * x);
  return (e - 1.f) / (e + 1.f);
}

// ---- fp32 -> fp16 convert, 4 elems/thread ----
__global__ void cvt_f32_f16(const float* __restrict__ in, _Float16* __restrict__ out, int n4) {
  int i = blockIdx.x * 256 + threadIdx.x;
  if (i >= n4) return;
  float4 v = ((const float4*)in)[i];
  union { _Float16 h[4]; unsigned long long u; } r;
  r.h[0] = (_Float16)v.x; r.h[1] = (_Float16)v.y;
  r.h[2] = (_Float16)v.z; r.h[3] = (_Float16)v.w;
  ((unsigned long long*)out)[i] = r.u;
}

// ---- phase 1: wx[bt][n] = sum_k x16[bt][k]*W16[n][k]; M=65536 N=2048 K=512 ----
__global__ __launch_bounds__(256, 2) void gemm_wx(const _Float16* __restrict__ A,
                                                  const _Float16* __restrict__ Bw,
                                                  _Float16* __restrict__ C) {
  const int bn = blockIdx.x;   // 0..15
  const int bm = blockIdx.y;   // 0..511
  const int tid = threadIdx.x;
  const int lane = tid & 63;
  const int w = tid >> 6;
  __shared__ _Float16 As[128 * 40];
  __shared__ _Float16 Bs[128 * 40];
  const int moff = (w & 1) * 64;
  const int noff = (w >> 1) * 64;
  const int fm = lane & 15;
  const int kq = lane >> 4;
  f32x4 acc[4][4] = {};
  for (int kt = 0; kt < 16; ++kt) {
#pragma unroll
    for (int e = 0; e < 2; ++e) {
      int ci = tid * 2 + e;
      int r = ci >> 2, c16 = ci & 3;
      half8 av = *(const half8*)(A + (size_t)(bm * 128 + r) * 512 + kt * 32 + c16 * 8);
      half8 bv = *(const half8*)(Bw + (size_t)(bn * 128 + r) * 512 + kt * 32 + c16 * 8);
      *(half8*)(As + r * 40 + c16 * 8) = av;
      *(half8*)(Bs + r * 40 + c16 * 8) = bv;
    }
    __syncthreads();
    half8 af[4], bf[4];
#pragma unroll
    for (int i = 0; i < 4; ++i) {
      af[i] = *(const half8*)(As + (moff + i * 16 + fm) * 40 + kq * 8);
      bf[i] = *(const half8*)(Bs + (noff + i * 16 + fm) * 40 + kq * 8);
    }
#pragma unroll
    for (int i = 0; i < 4; ++i)
#pragma unroll
      for (int j = 0; j < 4; ++j)
        acc[i][j] = __builtin_amdgcn_mfma_f32_16x16x32_f16(af[i], bf[j], acc[i][j], 0, 0, 0);
    __syncthreads();
  }
#pragma unroll
  for (int i = 0; i < 4; ++i) {
    int row = bm * 128 + moff + i * 16 + (lane >> 4) * 4;
#pragma unroll
    for (int j = 0; j < 4; ++j) {
      int col = bn * 128 + noff + j * 16 + (lane & 15);
#pragma unroll
      for (int r = 0; r < 4; ++r)
        C[(size_t)(row + r) * 2048 + col] = (_Float16)acc[i][j][r];
    }
  }
}

// ---- phase 2: persistent scan. 32 WGs, WG g owns h-cols [g*16, g*16+16). ----
// Sync redesign: per-WG flag slot per step (no contended RMW), relaxed agent-scope
// bypass polls by ALL waves (no acquire invalidates), hex read via relaxed agent
// atomic 8B loads (always-fresh from coherence point, hoisted for pipelining).
__global__ __launch_bounds__(256, 1) void slstm_scan(
    const _Float16* __restrict__ wx,   // [B*T, 2048]
    const _Float16* __restrict__ U16,  // [2048, 512]
    const float* __restrict__ Wb, const float* __restrict__ Ub,
    const float* __restrict__ alpha,
    _Float16* __restrict__ hex,        // [2][32][512] exchange
    int* __restrict__ flags,           // [T*32] one slot per (step, WG)
    float* __restrict__ out) {         // outs [32][2048][512] then h then c (fp32)
  const int g = blockIdx.x;
  const int tid = threadIdx.x;
  const int lane = tid & 63;
  const int w = tid >> 6;
  const int mi = w & 1;          // m half (batch 0..15 / 16..31)
  const int qA = (w >> 1) * 2;   // this wave's two gate groups
  const int ncol = lane & 15;
  const int kq = lane >> 4;
  const int am = mi * 16 + ncol; // batch row for A-fragment

  // persistent B fragments: B[n=lane&15][k=kq*8+j], n = gate row (qA+s)*512+g*16+ncol
  half8 Bf0[16], Bf1[16];
#pragma unroll
  for (int ks = 0; ks < 16; ++ks) {
    Bf0[ks] = *(const half8*)(U16 + (size_t)(qA * 512 + g * 16 + ncol) * 512 + ks * 32 + kq * 8);
    Bf1[ks] = *(const half8*)(U16 + (size_t)((qA + 1) * 512 + g * 16 + ncol) * 512 + ks * 32 + kq * 8);
  }

  // elementwise ownership: thread -> (batch eb, column pair jp)
  const int eb = tid >> 3;       // 0..31
  const int jp = tid & 7;        // 0..7
  const int gj0 = g * 16 + jp * 2;
  float bias0[4], bias1[4];
#pragma unroll
  for (int q = 0; q < 4; ++q) {
    bias0[q] = Wb[q * 512 + gj0] + Ub[q * 512 + gj0];
    bias1[q] = Wb[q * 512 + gj0 + 1] + Ub[q * 512 + gj0 + 1];
  }
  const float al0 = alpha[gj0], al1 = alpha[gj0 + 1];
  float c0 = 0.f, c1 = 0.f;

  __shared__ float Sg[4 * 32 * 18];       // gate tiles, padded rows (18 floats)
  __shared__ _Float16 Swx[4 * 32 * 16];   // wx staging

  // wx load mapping: thread -> (q=lq, b=lb, 8-col chunk lc)
  const int lq = tid >> 6;
  const int lb = (tid >> 1) & 31;
  const int lc = tid & 1;
  const _Float16* wxp = wx + (size_t)lb * TT * 2048 + lq * 512 + g * 16 + lc * 8;

  int spin_budget = 1 << 23;  // safety valve vs. eternal hang
  const int fl = lane & 31;   // flag slot this lane polls

  for (int t = 0; t < TT; ++t) {
    half8 wxv = *(const half8*)(wxp + (size_t)t * 2048);  // prefetch (independent of h)
    f32x4 acc0 = {0.f, 0.f, 0.f, 0.f}, acc1 = {0.f, 0.f, 0.f, 0.f};
    if (t > 0) {
      // every wave spins independently: relaxed bypass loads, no acquire, no barrier
      int* fp = flags + (size_t)(t - 1) * 32;
      int v;
      do {
        v = __hip_atomic_load(fp + fl, __ATOMIC_RELAXED, __HIP_MEMORY_SCOPE_AGENT);
        if (--spin_budget <= 0) break;
      } while (!__all(v != 0));
      asm volatile("" ::: "memory");  // pin data loads after spin exit
      // hex reads: agent-scope relaxed (bypass L1/L2 -> coherence point), hoisted
      unsigned long long* hb64 =
          (unsigned long long*)(hex + ((t & 1) ^ 1) * (BB * HH) + (size_t)am * HH);
      union { unsigned long long u[2]; half8 h; } af[16];
#pragma unroll
      for (int ks = 0; ks < 16; ++ks) {
        af[ks].u[0] = __hip_atomic_load(hb64 + ks * 8 + kq * 2,
                                        __ATOMIC_RELAXED, __HIP_MEMORY_SCOPE_AGENT);
        af[ks].u[1] = __hip_atomic_load(hb64 + ks * 8 + kq * 2 + 1,
                                        __ATOMIC_RELAXED, __HIP_MEMORY_SCOPE_AGENT);
      }
#pragma unroll
      for (int ks = 0; ks < 16; ++ks) {
        acc0 = __builtin_amdgcn_mfma_f32_16x16x32_f16(af[ks].h, Bf0[ks], acc0, 0, 0, 0);
        acc1 = __builtin_amdgcn_mfma_f32_16x16x32_f16(af[ks].h, Bf1[ks], acc1, 0, 0, 0);
      }
    }
    // stage wx + gate tiles into LDS (prev step's LDS readers are done: own flag
    // was only set after B2 of step t-1, and we observed it in the spin)
    *(half8*)(Swx + (lq * 32 + lb) * 16 + lc * 8) = wxv;
#pragma unroll
    for (int i = 0; i < 4; ++i) {
      int m = mi * 16 + kq * 4 + i;  // C/D row = batch
      Sg[(qA * 32 + m) * 18 + ncol] = acc0[i];
      Sg[((qA + 1) * 32 + m) * 18 + ncol] = acc1[i];
    }
    __syncthreads();  // B1: staging -> elementwise
    float p0[4], p1[4];
#pragma unroll
    for (int q = 0; q < 4; ++q) {
      const int so = (q * 32 + eb) * 18 + jp * 2;
      const int wo = (q * 32 + eb) * 16 + jp * 2;
      p0[q] = Sg[so] + (float)Swx[wo] + bias0[q];
      p1[q] = Sg[so + 1] + (float)Swx[wo + 1] + bias1[q];
    }
    float i0 = fsig(p0[0]), f0 = fsig(p0[1]), o0 = fsig(p0[2]), g0 = ftanh_(p0[3]);
    float i1 = fsig(p1[0]), f1 = fsig(p1[1]), o1 = fsig(p1[2]), g1 = ftanh_(p1[3]);
    c0 = al0 * (f0 * c0 + i0 * g0);
    c1 = al1 * (f1 * c1 + i1 * g1);
    float h0 = o0 * ftanh_(c0);
    float h1 = o1 * ftanh_(c1);
    // publish h slice (agent-scope bypass), complete it, then set this WG's flag
    union { _Float16 h[2]; unsigned int u; } pk;
    pk.h[0] = (_Float16)h0; pk.h[1] = (_Float16)h1;
    unsigned int* hx = (unsigned int*)hex + ((t & 1) * (BB * HH) + eb * HH + gj0) / 2;
    __hip_atomic_store(hx, pk.u, __ATOMIC_RELAXED, __HIP_MEMORY_SCOPE_AGENT);
    asm volatile("s_waitcnt vmcnt(0)" ::: "memory");  // h committed at coherence point
    __syncthreads();  // B2: all threads' h done + LDS reads done
    if (tid == 0)
      __hip_atomic_store(flags + (size_t)t * 32 + g, 1,
                         __ATOMIC_RELAXED, __HIP_MEMORY_SCOPE_AGENT);
    // outputs (off the critical path, after the signal)
    size_t ob = ((size_t)eb * TT + t) * HH + gj0;
    union { float f[2]; double d; } od;
    od.f[0] = h0; od.f[1] = h1;
    __builtin_nontemporal_store(od.d, (double*)(out + ob));
    if (t == TT - 1) {
      const size_t HB = (size_t)BB * TT * HH;
      out[HB + eb * HH + gj0] = h0;
      out[HB + eb * HH + gj0 + 1] = h1;
      out[HB + BB * HH + eb * HH + gj0] = c0;
      out[HB + BB * HH + eb * HH + gj0 + 1] = c1;
    }
  }
}

extern "C" void kernel_launch(void* const* d_in, const int* in_sizes, int n_in,
                              void* d_out, int out_size, void* d_ws, size_t ws_size,
                              hipStream_t stream) {
  (void)in_sizes; (void)n_in; (void)out_size; (void)ws_size;
  const float* x  = (const float*)d_in[0];
  const float* Ww = (const float*)d_in[1];
  const float* Wb = (const float*)d_in[2];
  const float* Uw = (const float*)d_in[3];
  const float* Ub = (const float*)d_in[4];
  const float* al = (const float*)d_in[5];
  float* out = (float*)d_out;

  char* p = (char*)d_ws;
  _Float16* x16  = (_Float16*)p; p += (size_t)BB * TT * 512 * 2;   // 64 MiB
  _Float16* wx16 = (_Float16*)p; p += (size_t)BB * TT * 2048 * 2;  // 256 MiB
  _Float16* U16  = (_Float16*)p; p += (size_t)2048 * 512 * 2;
  _Float16* W16  = (_Float16*)p; p += (size_t)2048 * 512 * 2;
  _Float16* hexb = (_Float16*)p; p += (size_t)2 * BB * HH * 2;
  int* flags     = (int*)p;      p += (size_t)TT * 32 * 4;

  (void)hipMemsetAsync(flags, 0, (size_t)TT * 32 * 4, stream);
  cvt_f32_f16<<<32768, 256, 0, stream>>>(x, x16, BB * TT * 512 / 4);
  cvt_f32_f16<<<1024, 256, 0, stream>>>(Ww, W16, 2048 * 512 / 4);
  cvt_f32_f16<<<1024, 256, 0, stream>>>(Uw, U16, 2048 * 512 / 4);
  gemm_wx<<<dim3(16, 512), 256, 0, stream>>>(x16, W16, wx16);
  slstm_scan<<<NWG, 256, 0, stream>>>(wx16, U16, Wb, Ub, al, hexb, flags, out);
}